// Round 1
// baseline (1192.831 us; speedup 1.0000x reference)
//
#include <hip/hip_runtime.h>
#include <hip/hip_bf16.h>
#include <cstdint>
#include <cstddef>

using bf16 = __hip_bfloat16;
typedef __attribute__((ext_vector_type(8))) short short8;
typedef __attribute__((ext_vector_type(4))) float f32x4;

// ---------------------------------------------------------------------------
// Exact posit(16, es=1) round-trip quantization, matching the JAX reference:
//   scale  = floor(log2(max(|x|,1e-30)))      -> exact via exponent bits
//   regime = floor(scale/2)                   -> arithmetic shift
//   rlen   = regime>=0 ? regime+2 : 1-regime
//   fbits  = clip(14 - rlen, 0, 28)           (upper clip never binds, max 12)
//   mq     = 1 + round((m-1)*2^fbits)/2^fbits (round-half-even == jnp.round)
//   mag    = clip(mq*2^scale, 2^-28, 2^28)
// All steps are exact power-of-two scalings -> bit-exact vs the math spec.
// ---------------------------------------------------------------------------
__device__ __forceinline__ float posit_quant_f32(float x) {
  float absx = fabsf(x);
  float safe = fmaxf(absx, 1e-30f);          // >= 1e-30 -> always normal
  uint32_t bits = __float_as_uint(safe);
  int scale = (int)((bits >> 23) & 0xFFu) - 127;
  int regime = scale >> 1;                   // floor(scale/2)
  int rlen = (regime >= 0) ? (regime + 2) : (1 - regime);
  int fbits = 14 - rlen;
  fbits = fbits < 0 ? 0 : fbits;
  float pw = (float)(1 << fbits);
  float m = __uint_as_float((bits & 0x007FFFFFu) | 0x3F800000u);  // safe*2^-scale in [1,2)
  float mq = rintf((m - 1.0f) * pw) * (1.0f / pw) + 1.0f;
  float mag = mq * __uint_as_float((uint32_t)(scale + 127) << 23);
  mag = fminf(fmaxf(mag, 0x1p-28f), 0x1p28f);
  return (absx == 0.0f) ? 0.0f : copysignf(mag, x);
}

// ---------------------------------------------------------------------------
// Elementwise: f32 -> posit_quant -> bf16 (RNE), vectorized 4-wide
// ---------------------------------------------------------------------------
__global__ void kquant_bf16(const float* __restrict__ in, bf16* __restrict__ out, long n4) {
  long i = (long)blockIdx.x * blockDim.x + threadIdx.x;
  long stride = (long)gridDim.x * blockDim.x;
  for (; i < n4; i += stride) {
    float4 v = ((const float4*)in)[i];
    ushort4 o;
    o.x = __builtin_bit_cast(unsigned short, __float2bfloat16(posit_quant_f32(v.x)));
    o.y = __builtin_bit_cast(unsigned short, __float2bfloat16(posit_quant_f32(v.y)));
    o.z = __builtin_bit_cast(unsigned short, __float2bfloat16(posit_quant_f32(v.z)));
    o.w = __builtin_bit_cast(unsigned short, __float2bfloat16(posit_quant_f32(v.w)));
    ((ushort4*)out)[i] = o;
  }
}

// bias: f32 -> posit_quant -> f32 (kept exact, added in fp32 epilogue)
__global__ void kquant_f32(const float* __restrict__ in, float* __restrict__ out, int n) {
  int i = blockIdx.x * blockDim.x + threadIdx.x;
  if (i < n) out[i] = posit_quant_f32(in[i]);
}

// ---------------------------------------------------------------------------
// BT-GEMM: C[m,n] = sum_k A[m,k] * B[n,k]   (both K-major, bf16)
// 128x128 tile, BK=32, 4 waves (2x2), 4x4 mfma_f32_16x16x32_bf16 per wave.
// global_load_lds width-16 staging (m97 structure, ~900 TF on gfx950).
// Epilogue: +bias, posit_quant, optional relu; store bf16 (hidden) or f32.
// ---------------------------------------------------------------------------
#define GBM 128
#define GBN 128
#define GBK 32

typedef __attribute__((address_space(1))) uint32_t gu32;
typedef __attribute__((address_space(3))) uint32_t lu32;

__device__ __forceinline__ void gload_lds16(const void* g, void* l) {
  __builtin_amdgcn_global_load_lds((const gu32*)g, (lu32*)l, 16, 0, 0);
}

template <bool RELU, bool OUTBF16>
__global__ __launch_bounds__(256, 2) void gemm_bt_posit(
    const bf16* __restrict__ A, const bf16* __restrict__ B,
    const float* __restrict__ bias, void* __restrict__ out,
    int M, int N, int K) {
  __shared__ __align__(1024) bf16 sA[GBM][GBK];  // 8 KB
  __shared__ __align__(1024) bf16 sB[GBN][GBK];  // 8 KB

  const int tid = threadIdx.x;
  const int lane = tid & 63;
  const int wave = tid >> 6;        // 0..3
  const int wr = wave >> 1;         // 0..1 : wave row in 2x2 grid
  const int wc = wave & 1;          // 0..1 : wave col
  const long brow0 = (long)blockIdx.y * GBM;
  const long bcol0 = (long)blockIdx.x * GBN;

  // Staging: 8 A-segments + 8 B-segments of 1 KB (16 rows x 64 B).
  // Wave w stages A segs {2w, 2w+1} and B segs {2w, 2w+1}.
  // Within a segment: lane l -> row seg*16 + l/4, col elems (l%4)*8 (16 B).
  const int srow = lane >> 2;           // 0..15
  const int scol = (lane & 3) * 8;      // 0,8,16,24
  const int seg0 = wave * 2;

  const bf16* gA0 = A + (brow0 + seg0 * 16 + srow) * (long)K + scol;
  const bf16* gA1 = A + (brow0 + seg0 * 16 + 16 + srow) * (long)K + scol;
  const bf16* gB0 = B + (bcol0 + seg0 * 16 + srow) * (long)K + scol;
  const bf16* gB1 = B + (bcol0 + seg0 * 16 + 16 + srow) * (long)K + scol;
  bf16* lA0 = (bf16*)sA + seg0 * 512;   // wave-uniform LDS base; HW adds lane*16B
  bf16* lA1 = lA0 + 512;
  bf16* lB0 = (bf16*)sB + seg0 * 512;
  bf16* lB1 = lB0 + 512;

  f32x4 acc[4][4] = {};

  const int fr = lane & 15;            // fragment row (A) / col (B)
  const int fk = (lane >> 4) * 8;      // k-offset within 32

  for (int kt = 0; kt < K; kt += GBK) {
    __syncthreads();                   // previous tile's ds_reads done
    gload_lds16(gA0 + kt, lA0);
    gload_lds16(gA1 + kt, lA1);
    gload_lds16(gB0 + kt, lB0);
    gload_lds16(gB1 + kt, lB1);
    __syncthreads();                   // staging complete (vmcnt(0) before barrier)

    short8 af[4], bfv[4];
#pragma unroll
    for (int i = 0; i < 4; ++i)
      af[i] = *(const short8*)&sA[wr * 64 + i * 16 + fr][fk];
#pragma unroll
    for (int j = 0; j < 4; ++j)
      bfv[j] = *(const short8*)&sB[wc * 64 + j * 16 + fr][fk];
#pragma unroll
    for (int i = 0; i < 4; ++i)
#pragma unroll
      for (int j = 0; j < 4; ++j)
        acc[i][j] = __builtin_amdgcn_mfma_f32_16x16x32_bf16(af[i], bfv[j], acc[i][j], 0, 0, 0);
  }

  // Epilogue. C/D layout (verified m89/m91): col = lane&15, row = (lane>>4)*4 + reg.
  const int orow = (lane >> 4) * 4;
  const long row0 = brow0 + wr * 64;
  const long col0 = bcol0 + wc * 64;
#pragma unroll
  for (int j = 0; j < 4; ++j) {
    const long col = col0 + j * 16 + fr;
    const float bv = bias[col];
#pragma unroll
    for (int i = 0; i < 4; ++i) {
#pragma unroll
      for (int q = 0; q < 4; ++q) {
        float v = acc[i][j][q] + bv;
        v = posit_quant_f32(v);
        if (RELU) v = fmaxf(v, 0.0f);
        const long idx = (row0 + i * 16 + orow + q) * (long)N + col;
        if (OUTBF16)
          ((bf16*)out)[idx] = __float2bfloat16(v);
        else
          ((float*)out)[idx] = v;
      }
    }
  }
}

// ---------------------------------------------------------------------------
extern "C" void kernel_launch(void* const* d_in, const int* in_sizes, int n_in,
                              void* d_out, int out_size, void* d_ws, size_t ws_size,
                              hipStream_t stream) {
  const float* x  = (const float*)d_in[0];   // (4096, 2048)
  const float* W0 = (const float*)d_in[1];   // (8192, 2048)
  const float* b0 = (const float*)d_in[2];   // (8192,)
  const float* W1 = (const float*)d_in[3];   // (8192, 8192)
  const float* b1 = (const float*)d_in[4];   // (8192,)
  const float* W2 = (const float*)d_in[5];   // (2048, 8192)
  const float* b2 = (const float*)d_in[6];   // (2048,)

  const int M = 4096, D0 = 2048, D1 = 8192, D2 = 8192, DO = 2048;

  char* ws = (char*)d_ws;
  size_t off = 0;
  auto alloc = [&](size_t bytes) {
    char* p = ws + off;
    off += (bytes + 255) & ~(size_t)255;
    return p;
  };
  bf16* xq  = (bf16*)alloc((size_t)M * D0 * 2);    // 16.8 MB
  bf16* W0q = (bf16*)alloc((size_t)D1 * D0 * 2);   // 33.6 MB
  bf16* W1q = (bf16*)alloc((size_t)D2 * D1 * 2);   // 134.2 MB
  bf16* W2q = (bf16*)alloc((size_t)DO * D2 * 2);   // 33.6 MB
  bf16* h0  = (bf16*)alloc((size_t)M * D1 * 2);    // 67.1 MB
  bf16* h1  = (bf16*)alloc((size_t)M * D2 * 2);    // 67.1 MB
  float* b0q = (float*)alloc((size_t)D1 * 4);
  float* b1q = (float*)alloc((size_t)D2 * 4);
  float* b2q = (float*)alloc((size_t)DO * 4);
  (void)ws_size; (void)in_sizes; (void)n_in; (void)out_size;

  auto quant = [&](const float* in, bf16* outp, long n) {
    long n4 = n / 4;
    long want = (n4 + 255) / 256;
    int blocks = (int)(want < 2048 ? want : 2048);
    kquant_bf16<<<blocks, 256, 0, stream>>>(in, outp, n4);
  };
  quant(x,  xq,  (long)M * D0);
  quant(W0, W0q, (long)D1 * D0);
  quant(W1, W1q, (long)D2 * D1);
  quant(W2, W2q, (long)DO * D2);
  kquant_f32<<<(D1 + 255) / 256, 256, 0, stream>>>(b0, b0q, D1);
  kquant_f32<<<(D2 + 255) / 256, 256, 0, stream>>>(b1, b1q, D2);
  kquant_f32<<<(DO + 255) / 256, 256, 0, stream>>>(b2, b2q, DO);

  dim3 blk(256);
  // L0: h0 = relu(pq(xq @ W0q^T + b0q))          M=4096 N=8192 K=2048
  gemm_bt_posit<true, true><<<dim3(D1 / GBN, M / GBM), blk, 0, stream>>>(
      xq, W0q, b0q, h0, M, D1, D0);
  // L1: h1 = relu(pq(h0 @ W1q^T + b1q))          M=4096 N=8192 K=8192
  gemm_bt_posit<true, true><<<dim3(D2 / GBN, M / GBM), blk, 0, stream>>>(
      h0, W1q, b1q, h1, M, D2, D1);
  // L2: out = pq(h1 @ W2q^T + b2q)  (f32 out)    M=4096 N=2048 K=8192
  gemm_bt_posit<false, false><<<dim3(DO / GBN, M / GBM), blk, 0, stream>>>(
      h1, W2q, b2q, (float*)d_out, M, DO, D2);
}

// Round 2
// 941.128 us; speedup vs baseline: 1.2674x; 1.2674x over previous
//
#include <hip/hip_runtime.h>
#include <hip/hip_bf16.h>
#include <cstdint>
#include <cstddef>

using bf16 = __hip_bfloat16;
typedef __attribute__((ext_vector_type(8))) short short8;
typedef __attribute__((ext_vector_type(4))) float f32x4;

// ---------------------------------------------------------------------------
// Exact posit(16, es=1) round-trip quantization (see round-1 derivation).
// ---------------------------------------------------------------------------
__device__ __forceinline__ float posit_quant_f32(float x) {
  float absx = fabsf(x);
  float safe = fmaxf(absx, 1e-30f);
  uint32_t bits = __float_as_uint(safe);
  int scale = (int)((bits >> 23) & 0xFFu) - 127;
  int regime = scale >> 1;
  int rlen = (regime >= 0) ? (regime + 2) : (1 - regime);
  int fbits = 14 - rlen;
  fbits = fbits < 0 ? 0 : fbits;
  float pw = (float)(1 << fbits);
  float m = __uint_as_float((bits & 0x007FFFFFu) | 0x3F800000u);
  float mq = rintf((m - 1.0f) * pw) * (1.0f / pw) + 1.0f;
  float mag = mq * __uint_as_float((uint32_t)(scale + 127) << 23);
  mag = fminf(fmaxf(mag, 0x1p-28f), 0x1p28f);
  return (absx == 0.0f) ? 0.0f : copysignf(mag, x);
}

__global__ void kquant_bf16(const float* __restrict__ in, bf16* __restrict__ out, long n4) {
  long i = (long)blockIdx.x * blockDim.x + threadIdx.x;
  long stride = (long)gridDim.x * blockDim.x;
  for (; i < n4; i += stride) {
    float4 v = ((const float4*)in)[i];
    ushort4 o;
    o.x = __builtin_bit_cast(unsigned short, __float2bfloat16(posit_quant_f32(v.x)));
    o.y = __builtin_bit_cast(unsigned short, __float2bfloat16(posit_quant_f32(v.y)));
    o.z = __builtin_bit_cast(unsigned short, __float2bfloat16(posit_quant_f32(v.z)));
    o.w = __builtin_bit_cast(unsigned short, __float2bfloat16(posit_quant_f32(v.w)));
    ((ushort4*)out)[i] = o;
  }
}

__global__ void kquant_f32(const float* __restrict__ in, float* __restrict__ out, int n) {
  int i = blockIdx.x * blockDim.x + threadIdx.x;
  if (i < n) out[i] = posit_quant_f32(in[i]);
}

typedef __attribute__((address_space(1))) uint32_t gu32;
typedef __attribute__((address_space(3))) uint32_t lu32;

// ===========================================================================
// 256x256 tile, BK=64, 8 waves (2x4), 8-phase schedule, counted vmcnt,
// LDS XOR-swizzle (read-side + inverse-swizzled gload source), setprio,
// XCD-aware block swizzle. BT layout: C[m,n] = sum_k A[m,k]*B[n,k].
// LDS map: A buf0 [0,32K) A buf1 [32K,64K) B buf0 [64K,96K) B buf1 [96K,128K)
// Operand buffer: 256 rows x 64 bf16, 128 B/row, row-major.
// Swizzle: byte_in_row ^= ((row&7)<<4).
// ===========================================================================
#define SBAR()  do { __builtin_amdgcn_sched_barrier(0); __builtin_amdgcn_s_barrier(); \
                     __builtin_amdgcn_sched_barrier(0); } while (0)
#define LGKM0() do { asm volatile("s_waitcnt lgkmcnt(0)" ::: "memory"); \
                     __builtin_amdgcn_sched_barrier(0); } while (0)
#define VMCNT(N) asm volatile("s_waitcnt vmcnt(" #N ")" ::: "memory")

#define STG_A(BUF, H, KT) do { \
    const char* _s = srcA + (long)((H) * 128) * Kb + (long)(KT) * 128; \
    char* _d = smem + (BUF) * 32768 + (H) * 16384 + dA; \
    __builtin_amdgcn_global_load_lds((const gu32*)_s, (lu32*)_d, 16, 0, 0); \
    __builtin_amdgcn_global_load_lds((const gu32*)(_s + 64 * Kb), (lu32*)(_d + 8192), 16, 0, 0); \
  } while (0)
#define STG_B(BUF, H, KT) do { \
    const char* _s = srcB + (long)((H) * 128) * Kb + (long)(KT) * 128; \
    char* _d = smem + (BUF) * 32768 + (H) * 16384 + dB; \
    __builtin_amdgcn_global_load_lds((const gu32*)_s, (lu32*)_d, 16, 0, 0); \
    __builtin_amdgcn_global_load_lds((const gu32*)(_s + 64 * Kb), (lu32*)(_d + 8192), 16, 0, 0); \
  } while (0)

#define LDA8(BUF, FI, CK) (*(const short8*)(smem + (BUF) * 32768 + aBase + (FI) * 2048 + (CK)))
#define LDB8(BUF, FJ, CK) (*(const short8*)(smem + (BUF) * 32768 + bBase + (FJ) * 2048 + (CK)))

#define MQ(FI0, FJ0) do { \
    _Pragma("unroll") \
    for (int fi = 0; fi < 4; ++fi) { \
      _Pragma("unroll") \
      for (int fj = 0; fj < 2; ++fj) { \
        acc[(FI0) + fi][(FJ0) + fj] = __builtin_amdgcn_mfma_f32_16x16x32_bf16( \
            afr[fi][0], bfr[(FJ0) + fj][0], acc[(FI0) + fi][(FJ0) + fj], 0, 0, 0); \
        acc[(FI0) + fi][(FJ0) + fj] = __builtin_amdgcn_mfma_f32_16x16x32_bf16( \
            afr[fi][1], bfr[(FJ0) + fj][1], acc[(FI0) + fi][(FJ0) + fj], 0, 0, 0); \
      } \
    } \
  } while (0)

template <bool RELU, bool OUTBF16>
__global__ __launch_bounds__(512, 2) void gemm256_posit(
    const bf16* __restrict__ A, const bf16* __restrict__ B,
    const float* __restrict__ bias, void* __restrict__ out,
    int M, int N, int K, int nbx, int cpx) {
  __shared__ char smem[131072];

  const int tid  = threadIdx.x;
  const int lane = tid & 63;
  const int wave = tid >> 6;        // 0..7
  const int wr = wave >> 2;         // 0..1  (M half)
  const int wc = wave & 3;          // 0..3  (N quarter)

  // XCD-aware bijective swizzle (grid is a multiple of 8 here)
  const int flat = blockIdx.x;
  const int wgid = (flat & 7) * cpx + (flat >> 3);
  const long brow0 = (long)(wgid / nbx) * 256;
  const long bcol0 = (long)(wgid % nbx) * 256;

  const long Kb = (long)K * 2;
  // staging source (per-lane, inverse-swizzled so linear LDS dest + swizzled
  // read yields correct data; XOR is an involution)
  const int srow = tid >> 3;                                   // 0..63
  const int scb  = ((tid & 7) * 16) ^ (((tid >> 3) & 7) << 4); // swizzled col byte
  const char* srcA = (const char*)A + (brow0 + srow) * Kb + scb;
  const char* srcB = (const char*)B + (bcol0 + srow) * Kb + scb;
  // staging dest (wave-uniform; HW adds lane*16)
  const int dA = wave * 1024;
  const int dB = 65536 + wave * 1024;

  // fragment read addressing (mfma_f32_16x16x32_bf16: row=lane&15, k=(lane>>4)*8)
  const int fr  = lane & 15;
  const int swz = (lane & 7) << 4;                 // (row&7)<<4, row%8 == lane%8
  const int ck0 = (((lane >> 4) << 4)) ^ swz;      // kk=0 col byte (swizzled)
  const int ck1 = (64 + ((lane >> 4) << 4)) ^ swz; // kk=1
  const int aBase = wr * 16384 + fr * 128;
  const int bBase = 65536 + wc * 8192 + fr * 128;

  f32x4 acc[8][4] = {};
  short8 afr[4][2], bfr[4][2];

  const int nkt = K >> 6;     // K / 64 (power of 2: 32 or 128)
  const int np  = nkt >> 1;

  // Prologue: tile0 (B then A) + tile1 B. vmcnt(4) completes tile0's 8 loads.
  STG_B(0, 0, 0); STG_B(0, 1, 0);
  STG_A(0, 0, 0); STG_A(0, 1, 0);
  STG_B(1, 0, 1); STG_B(1, 1, 1);
  VMCNT(4);
  SBAR();

#pragma unroll 1
  for (int i = 0; i < np; ++i) {
    const int kA1 = 2 * i + 1;
    const int kS2 = (2 * i + 2) & (nkt - 1);  // tail wraps: harmless re-stage
    const int kS3 = (2 * i + 3) & (nkt - 1);

    // phase 1: tile t0 (buf0) quadrant (0,0); stage A(t0+1) h0 -> buf1
#pragma unroll
    for (int f = 0; f < 4; ++f) { afr[f][0] = LDA8(0, f, ck0); afr[f][1] = LDA8(0, f, ck1); }
#pragma unroll
    for (int f = 0; f < 2; ++f) { bfr[f][0] = LDB8(0, f, ck0); bfr[f][1] = LDB8(0, f, ck1); }
    STG_A(1, 0, kA1);
    SBAR(); LGKM0();
    __builtin_amdgcn_s_setprio(1); MQ(0, 0); __builtin_amdgcn_s_setprio(0);
    SBAR();

    // phase 2: quadrant (0,1); stage A(t0+1) h1
#pragma unroll
    for (int f = 2; f < 4; ++f) { bfr[f][0] = LDB8(0, f, ck0); bfr[f][1] = LDB8(0, f, ck1); }
    STG_A(1, 1, kA1);
    SBAR(); LGKM0();
    __builtin_amdgcn_s_setprio(1); MQ(0, 2); __builtin_amdgcn_s_setprio(0);
    SBAR();

    // phase 3: quadrant (1,0); stage B(t0+2) h0 -> buf0 (B region free after ph2)
#pragma unroll
    for (int f = 0; f < 4; ++f) { afr[f][0] = LDA8(0, f + 4, ck0); afr[f][1] = LDA8(0, f + 4, ck1); }
    STG_B(0, 0, kS2);
    SBAR(); LGKM0();
    __builtin_amdgcn_s_setprio(1); MQ(4, 0); __builtin_amdgcn_s_setprio(0);
    SBAR();

    // phase 4: quadrant (1,1); stage B(t0+2) h1; counted vmcnt -> tile t0+1 ready
    STG_B(0, 1, kS2);
    VMCNT(4);
    SBAR();
    __builtin_amdgcn_s_setprio(1); MQ(4, 2); __builtin_amdgcn_s_setprio(0);
    SBAR();

    // phase 5: tile t1 (buf1) quadrant (0,0); stage A(t0+2) h0 -> buf0 (A free after ph3)
#pragma unroll
    for (int f = 0; f < 4; ++f) { afr[f][0] = LDA8(1, f, ck0); afr[f][1] = LDA8(1, f, ck1); }
#pragma unroll
    for (int f = 0; f < 2; ++f) { bfr[f][0] = LDB8(1, f, ck0); bfr[f][1] = LDB8(1, f, ck1); }
    STG_A(0, 0, kS2);
    SBAR(); LGKM0();
    __builtin_amdgcn_s_setprio(1); MQ(0, 0); __builtin_amdgcn_s_setprio(0);
    SBAR();

    // phase 6: quadrant (0,1); stage A(t0+2) h1
#pragma unroll
    for (int f = 2; f < 4; ++f) { bfr[f][0] = LDB8(1, f, ck0); bfr[f][1] = LDB8(1, f, ck1); }
    STG_A(0, 1, kS2);
    SBAR(); LGKM0();
    __builtin_amdgcn_s_setprio(1); MQ(0, 2); __builtin_amdgcn_s_setprio(0);
    SBAR();

    // phase 7: quadrant (1,0); stage B(t0+3) h0 -> buf1 (B free after ph6)
#pragma unroll
    for (int f = 0; f < 4; ++f) { afr[f][0] = LDA8(1, f + 4, ck0); afr[f][1] = LDA8(1, f + 4, ck1); }
    STG_B(1, 0, kS3);
    SBAR(); LGKM0();
    __builtin_amdgcn_s_setprio(1); MQ(4, 0); __builtin_amdgcn_s_setprio(0);
    SBAR();

    // phase 8: quadrant (1,1); stage B(t0+3) h1; counted vmcnt -> next t0 ready
    STG_B(1, 1, kS3);
    VMCNT(4);
    SBAR();
    __builtin_amdgcn_s_setprio(1); MQ(4, 2); __builtin_amdgcn_s_setprio(0);
    SBAR();
  }
  asm volatile("s_waitcnt vmcnt(0)" ::: "memory");  // drain dangling DMA

  // Epilogue: C/D layout col=lane&15, row=(lane>>4)*4+q (verified round 1)
  const int orow = (lane >> 4) * 4;
  const long row0 = brow0 + wr * 128;
  const long col0 = bcol0 + wc * 64;
#pragma unroll
  for (int fj = 0; fj < 4; ++fj) {
    const long col = col0 + fj * 16 + fr;
    const float bv = bias[col];
#pragma unroll
    for (int fi = 0; fi < 8; ++fi) {
#pragma unroll
      for (int q = 0; q < 4; ++q) {
        float v = acc[fi][fj][q] + bv;
        v = posit_quant_f32(v);
        if (RELU) v = fmaxf(v, 0.0f);
        const long idx = (row0 + fi * 16 + orow + q) * (long)N + col;
        if (OUTBF16) ((bf16*)out)[idx] = __float2bfloat16(v);
        else         ((float*)out)[idx] = v;
      }
    }
  }
}

// ===========================================================================
// Round-1 128x128 m97-structure kernel (kept for L2: N=2048 -> 512 blocks)
// ===========================================================================
#define GBM 128
#define GBN 128
#define GBK 32

__device__ __forceinline__ void gload_lds16(const void* g, void* l) {
  __builtin_amdgcn_global_load_lds((const gu32*)g, (lu32*)l, 16, 0, 0);
}

template <bool RELU, bool OUTBF16>
__global__ __launch_bounds__(256, 2) void gemm_bt_posit(
    const bf16* __restrict__ A, const bf16* __restrict__ B,
    const float* __restrict__ bias, void* __restrict__ out,
    int M, int N, int K) {
  __shared__ __align__(1024) bf16 sA[GBM][GBK];
  __shared__ __align__(1024) bf16 sB[GBN][GBK];

  const int tid = threadIdx.x;
  const int lane = tid & 63;
  const int wave = tid >> 6;
  const int wr = wave >> 1;
  const int wc = wave & 1;
  const long brow0 = (long)blockIdx.y * GBM;
  const long bcol0 = (long)blockIdx.x * GBN;

  const int srow = lane >> 2;
  const int scol = (lane & 3) * 8;
  const int seg0 = wave * 2;

  const bf16* gA0 = A + (brow0 + seg0 * 16 + srow) * (long)K + scol;
  const bf16* gA1 = A + (brow0 + seg0 * 16 + 16 + srow) * (long)K + scol;
  const bf16* gB0 = B + (bcol0 + seg0 * 16 + srow) * (long)K + scol;
  const bf16* gB1 = B + (bcol0 + seg0 * 16 + 16 + srow) * (long)K + scol;
  bf16* lA0 = (bf16*)sA + seg0 * 512;
  bf16* lA1 = lA0 + 512;
  bf16* lB0 = (bf16*)sB + seg0 * 512;
  bf16* lB1 = lB0 + 512;

  f32x4 acc[4][4] = {};
  const int fr = lane & 15;
  const int fk = (lane >> 4) * 8;

  for (int kt = 0; kt < K; kt += GBK) {
    __syncthreads();
    gload_lds16(gA0 + kt, lA0);
    gload_lds16(gA1 + kt, lA1);
    gload_lds16(gB0 + kt, lB0);
    gload_lds16(gB1 + kt, lB1);
    __syncthreads();

    short8 af[4], bfv[4];
#pragma unroll
    for (int i = 0; i < 4; ++i) af[i] = *(const short8*)&sA[wr * 64 + i * 16 + fr][fk];
#pragma unroll
    for (int j = 0; j < 4; ++j) bfv[j] = *(const short8*)&sB[wc * 64 + j * 16 + fr][fk];
#pragma unroll
    for (int i = 0; i < 4; ++i)
#pragma unroll
      for (int j = 0; j < 4; ++j)
        acc[i][j] = __builtin_amdgcn_mfma_f32_16x16x32_bf16(af[i], bfv[j], acc[i][j], 0, 0, 0);
  }

  const int orow = (lane >> 4) * 4;
  const long row0 = brow0 + wr * 64;
  const long col0 = bcol0 + wc * 64;
#pragma unroll
  for (int j = 0; j < 4; ++j) {
    const long col = col0 + j * 16 + fr;
    const float bv = bias[col];
#pragma unroll
    for (int i = 0; i < 4; ++i) {
#pragma unroll
      for (int q = 0; q < 4; ++q) {
        float v = acc[i][j][q] + bv;
        v = posit_quant_f32(v);
        if (RELU) v = fmaxf(v, 0.0f);
        const long idx = (row0 + i * 16 + orow + q) * (long)N + col;
        if (OUTBF16) ((bf16*)out)[idx] = __float2bfloat16(v);
        else         ((float*)out)[idx] = v;
      }
    }
  }
}

// ---------------------------------------------------------------------------
extern "C" void kernel_launch(void* const* d_in, const int* in_sizes, int n_in,
                              void* d_out, int out_size, void* d_ws, size_t ws_size,
                              hipStream_t stream) {
  const float* x  = (const float*)d_in[0];
  const float* W0 = (const float*)d_in[1];
  const float* b0 = (const float*)d_in[2];
  const float* W1 = (const float*)d_in[3];
  const float* b1 = (const float*)d_in[4];
  const float* W2 = (const float*)d_in[5];
  const float* b2 = (const float*)d_in[6];

  const int M = 4096, D0 = 2048, D1 = 8192, D2 = 8192, DO = 2048;

  char* ws = (char*)d_ws;
  size_t off = 0;
  auto alloc = [&](size_t bytes) {
    char* p = ws + off;
    off += (bytes + 255) & ~(size_t)255;
    return p;
  };
  bf16* xq  = (bf16*)alloc((size_t)M * D0 * 2);
  bf16* W0q = (bf16*)alloc((size_t)D1 * D0 * 2);
  bf16* W1q = (bf16*)alloc((size_t)D2 * D1 * 2);
  bf16* W2q = (bf16*)alloc((size_t)DO * D2 * 2);
  bf16* h0  = (bf16*)alloc((size_t)M * D1 * 2);
  bf16* h1  = (bf16*)alloc((size_t)M * D2 * 2);
  float* b0q = (float*)alloc((size_t)D1 * 4);
  float* b1q = (float*)alloc((size_t)D2 * 4);
  float* b2q = (float*)alloc((size_t)DO * 4);
  (void)ws_size; (void)in_sizes; (void)n_in; (void)out_size;

  auto quant = [&](const float* in, bf16* outp, long n) {
    long n4 = n / 4;
    long want = (n4 + 255) / 256;
    int blocks = (int)(want < 2048 ? want : 2048);
    kquant_bf16<<<blocks, 256, 0, stream>>>(in, outp, n4);
  };
  quant(x,  xq,  (long)M * D0);
  quant(W0, W0q, (long)D1 * D0);
  quant(W1, W1q, (long)D2 * D1);
  quant(W2, W2q, (long)DO * D2);
  kquant_f32<<<(D1 + 255) / 256, 256, 0, stream>>>(b0, b0q, D1);
  kquant_f32<<<(D2 + 255) / 256, 256, 0, stream>>>(b1, b1q, D2);
  kquant_f32<<<(DO + 255) / 256, 256, 0, stream>>>(b2, b2q, DO);

  // L0: h0 = relu(pq(xq @ W0q^T + b0q))   M=4096 N=8192 K=2048  (256^2 8-phase)
  {
    int nbx = D1 / 256, nwg = nbx * (M / 256);
    gemm256_posit<true, true><<<dim3(nwg), dim3(512), 0, stream>>>(
        xq, W0q, b0q, h0, M, D1, D0, nbx, nwg / 8);
  }
  // L1: h1 = relu(pq(h0 @ W1q^T + b1q))   M=4096 N=8192 K=8192  (256^2 8-phase)
  {
    int nbx = D2 / 256, nwg = nbx * (M / 256);
    gemm256_posit<true, true><<<dim3(nwg), dim3(512), 0, stream>>>(
        h0, W1q, b1q, h1, M, D2, D1, nbx, nwg / 8);
  }
  // L2: out = pq(h1 @ W2q^T + b2q)  f32   M=4096 N=2048 K=8192  (128^2, full grid)
  gemm_bt_posit<false, false><<<dim3(DO / GBN, M / GBM), dim3(256), 0, stream>>>(
      h1, W2q, b2q, (float*)d_out, M, DO, D2);
}

// Round 3
// 894.594 us; speedup vs baseline: 1.3334x; 1.0520x over previous
//
#include <hip/hip_runtime.h>
#include <hip/hip_bf16.h>
#include <cstdint>
#include <cstddef>

using bf16 = __hip_bfloat16;
typedef __attribute__((ext_vector_type(8))) short short8;
typedef __attribute__((ext_vector_type(4))) float f32x4;

// ---------------------------------------------------------------------------
// Exact posit(16, es=1) round-trip quantization (round-1 derivation).
// ---------------------------------------------------------------------------
__device__ __forceinline__ float posit_quant_f32(float x) {
  float absx = fabsf(x);
  float safe = fmaxf(absx, 1e-30f);
  uint32_t bits = __float_as_uint(safe);
  int scale = (int)((bits >> 23) & 0xFFu) - 127;
  int regime = scale >> 1;
  int rlen = (regime >= 0) ? (regime + 2) : (1 - regime);
  int fbits = 14 - rlen;
  fbits = fbits < 0 ? 0 : fbits;
  float pw = (float)(1 << fbits);
  float m = __uint_as_float((bits & 0x007FFFFFu) | 0x3F800000u);
  float mq = rintf((m - 1.0f) * pw) * (1.0f / pw) + 1.0f;
  float mag = mq * __uint_as_float((uint32_t)(scale + 127) << 23);
  mag = fminf(fmaxf(mag, 0x1p-28f), 0x1p28f);
  return (absx == 0.0f) ? 0.0f : copysignf(mag, x);
}

__global__ void kquant_bf16(const float* __restrict__ in, bf16* __restrict__ out, long n4) {
  long i = (long)blockIdx.x * blockDim.x + threadIdx.x;
  long stride = (long)gridDim.x * blockDim.x;
  for (; i < n4; i += stride) {
    float4 v = ((const float4*)in)[i];
    ushort4 o;
    o.x = __builtin_bit_cast(unsigned short, __float2bfloat16(posit_quant_f32(v.x)));
    o.y = __builtin_bit_cast(unsigned short, __float2bfloat16(posit_quant_f32(v.y)));
    o.z = __builtin_bit_cast(unsigned short, __float2bfloat16(posit_quant_f32(v.z)));
    o.w = __builtin_bit_cast(unsigned short, __float2bfloat16(posit_quant_f32(v.w)));
    ((ushort4*)out)[i] = o;
  }
}

// combine split-K partials: out = pq(p0 + p1 + pq(bias))
__global__ void kcombine(const float* __restrict__ p, const float* __restrict__ bias,
                         float* __restrict__ out, long n4, long halfn, int cmask) {
  long i = (long)blockIdx.x * blockDim.x + threadIdx.x;
  long stride = (long)gridDim.x * blockDim.x;
  for (; i < n4; i += stride) {
    float4 a = ((const float4*)p)[i];
    float4 b = ((const float4*)(p + halfn))[i];
    int c0 = (int)(i & cmask) * 4;
    float4 o;
    o.x = posit_quant_f32(a.x + b.x + posit_quant_f32(bias[c0 + 0]));
    o.y = posit_quant_f32(a.y + b.y + posit_quant_f32(bias[c0 + 1]));
    o.z = posit_quant_f32(a.z + b.z + posit_quant_f32(bias[c0 + 2]));
    o.w = posit_quant_f32(a.w + b.w + posit_quant_f32(bias[c0 + 3]));
    ((float4*)out)[i] = o;
  }
}

typedef __attribute__((address_space(1))) uint32_t gu32;
typedef __attribute__((address_space(3))) uint32_t lu32;

// ===========================================================================
// 256x256 tile, BK=64, 8 waves (2x4), 8-phase schedule.
// A TRIPLE-buffered (3x32K), B double-buffered (2x32K) -> 160 KiB LDS.
// All stages issued a full iteration ahead; vmcnt(8) at ph4/ph8 keeps 8
// loads in flight with stage-to-wait distance >= 4 phases (covers HBM lat).
// LDS map: A bufs at 0/32768/65536 (rotating), B bufs at 98304/131072.
// Row-major 128 B/row; swizzle byte_in_row ^= ((row&7)<<4), applied
// inverse-swizzled on the global source (gload_lds writes linearly).
// MODE: 0 = bias+pq+relu, bf16 out; 1 = bias+pq, f32 out; 2 = raw f32 partial.
// ===========================================================================
#define SBAR()  do { __builtin_amdgcn_sched_barrier(0); __builtin_amdgcn_s_barrier(); \
                     __builtin_amdgcn_sched_barrier(0); } while (0)
#define LGKM0() do { asm volatile("s_waitcnt lgkmcnt(0)" ::: "memory"); \
                     __builtin_amdgcn_sched_barrier(0); } while (0)
#define VMCNT(N) asm volatile("s_waitcnt vmcnt(" #N ")" ::: "memory")

// Stage 128 rows (half tile) of SRC K-tile KT into LDS offset DST (+H*16384)
#define STG(SRC, KT, H, DST) do { \
    const char* _s = (SRC) + (long)((H) * 128) * Kb + (long)(KT) * 128; \
    char* _d = smem + (DST) + (H) * 16384 + wave * 1024; \
    __builtin_amdgcn_global_load_lds((const gu32*)_s, (lu32*)_d, 16, 0, 0); \
    __builtin_amdgcn_global_load_lds((const gu32*)(_s + 64 * Kb), (lu32*)(_d + 8192), 16, 0, 0); \
  } while (0)

#define LDA8(AOFF, FI, CK) (*(const short8*)(smem + (AOFF) + aRel + (FI) * 2048 + (CK)))
#define LDB8(BOFF, FJ, CK) (*(const short8*)(smem + (BOFF) + bRel + (FJ) * 2048 + (CK)))

#define BB0 98304
#define BB1 131072

#define MQ(FI0, FJ0) do { \
    _Pragma("unroll") \
    for (int fi = 0; fi < 4; ++fi) { \
      _Pragma("unroll") \
      for (int fj = 0; fj < 2; ++fj) { \
        acc[(FI0) + fi][(FJ0) + fj] = __builtin_amdgcn_mfma_f32_16x16x32_bf16( \
            afr[fi][0], bfr[(FJ0) + fj][0], acc[(FI0) + fi][(FJ0) + fj], 0, 0, 0); \
        acc[(FI0) + fi][(FJ0) + fj] = __builtin_amdgcn_mfma_f32_16x16x32_bf16( \
            afr[fi][1], bfr[(FJ0) + fj][1], acc[(FI0) + fi][(FJ0) + fj], 0, 0, 0); \
      } \
    } \
  } while (0)

template <int MODE>
__global__ __launch_bounds__(512, 2) void gemm256_posit(
    const bf16* __restrict__ A, const bf16* __restrict__ B,
    const float* __restrict__ bias, void* __restrict__ out,
    int M, int N, int Kfull, int Kloop, int nbt, int cpx) {
  __shared__ __align__(1024) char smem[163840];

  const int tid  = threadIdx.x;
  const int lane = tid & 63;
  const int wave = tid >> 6;
  const int wr = wave >> 2;         // 0..1  (M half)
  const int wc = wave & 3;          // 0..3  (N quarter)

  // XCD-aware bijective swizzle (grid multiple of 8), then split-K decode
  const int flat = blockIdx.x;
  const int wgid = (flat & 7) * cpx + (flat >> 3);
  const int split = wgid / nbt;               // 0 unless split-K
  const int t = wgid - split * nbt;
  const int nbx = N >> 8;
  const long brow0 = (long)(t / nbx) * 256;
  const long bcol0 = (long)(t % nbx) * 256;

  const long Kb = (long)Kfull * 2;            // row stride bytes
  const long splitoff = (long)split * Kloop * 2;

  // staging source (per-lane, inverse-swizzled)
  const int srow = tid >> 3;                                   // 0..63
  const int scb  = ((tid & 7) * 16) ^ (((tid >> 3) & 7) << 4);
  const char* srcA = (const char*)A + (brow0 + srow) * Kb + scb + splitoff;
  const char* srcB = (const char*)B + (bcol0 + srow) * Kb + scb + splitoff;

  // fragment read addressing (mfma_f32_16x16x32_bf16: row=lane&15, k=(lane>>4)*8)
  const int fr  = lane & 15;
  const int swz = (lane & 7) << 4;
  const int ck0 = (((lane >> 4) << 4)) ^ swz;
  const int ck1 = (64 + ((lane >> 4) << 4)) ^ swz;
  const int aRel = wr * 16384 + fr * 128;
  const int bRel = wc * 8192 + fr * 128;

  f32x4 acc[8][4] = {};
  short8 afr[4][2], bfr[4][2];

  const int nkt = Kloop >> 6;     // tiles (power of 2)
  const int np  = nkt >> 1;

  // A buffer rotation: a0 = tile T0, a1 = T0+1, a2 = stage target (T0+2)
  int a0 = 0, a1 = 32768, a2 = 65536;

  // Prologue: A0,B0 then A1,B1 (16 loads); vmcnt(8) completes tile 0.
  STG(srcA, 0, 0, 0);     STG(srcA, 0, 1, 0);
  STG(srcB, 0, 0, BB0);   STG(srcB, 0, 1, BB0);
  STG(srcA, 1, 0, 32768); STG(srcA, 1, 1, 32768);
  STG(srcB, 1, 0, BB1);   STG(srcB, 1, 1, BB1);
  VMCNT(8);
  SBAR();

#pragma unroll 1
  for (int i = 0; i < np; ++i) {
    const int kS2 = (2 * i + 2) & (nkt - 1);  // tail wraps: harmless re-stage
    const int kS3 = (2 * i + 3) & (nkt - 1);

    // ph1: tile T0 (a0/BB0) quadrant (0,0); stage A(T0+2)h0 -> a2
#pragma unroll
    for (int f = 0; f < 4; ++f) { afr[f][0] = LDA8(a0, f, ck0); afr[f][1] = LDA8(a0, f, ck1); }
#pragma unroll
    for (int f = 0; f < 2; ++f) { bfr[f][0] = LDB8(BB0, f, ck0); bfr[f][1] = LDB8(BB0, f, ck1); }
    STG(srcA, kS2, 0, a2);
    SBAR(); LGKM0();
    __builtin_amdgcn_s_setprio(1); MQ(0, 0); __builtin_amdgcn_s_setprio(0);
    SBAR();

    // ph2: quadrant (0,1); stage A(T0+2)h1 -> a2
#pragma unroll
    for (int f = 2; f < 4; ++f) { bfr[f][0] = LDB8(BB0, f, ck0); bfr[f][1] = LDB8(BB0, f, ck1); }
    STG(srcA, kS2, 1, a2);
    SBAR(); LGKM0();
    __builtin_amdgcn_s_setprio(1); MQ(0, 2); __builtin_amdgcn_s_setprio(0);
    SBAR();

    // ph3: quadrant (1,0); stage B(T0+2)h0 -> BB0 (B buf0 free after ph2)
#pragma unroll
    for (int f = 0; f < 4; ++f) { afr[f][0] = LDA8(a0, f + 4, ck0); afr[f][1] = LDA8(a0, f + 4, ck1); }
    STG(srcB, kS2, 0, BB0);
    SBAR(); LGKM0();
    __builtin_amdgcn_s_setprio(1); MQ(4, 0); __builtin_amdgcn_s_setprio(0);
    SBAR();

    // ph4: quadrant (1,1); stage B(T0+2)h1; vmcnt(8) -> tile T0+1 (a1/BB1) ready
    STG(srcB, kS2, 1, BB0);
    VMCNT(8);
    SBAR();
    __builtin_amdgcn_s_setprio(1); MQ(4, 2); __builtin_amdgcn_s_setprio(0);
    SBAR();

    // ph5: tile T0+1 (a1/BB1) quadrant (0,0); stage A(T0+3)h0 -> a0 (A T0 free after ph3)
#pragma unroll
    for (int f = 0; f < 4; ++f) { afr[f][0] = LDA8(a1, f, ck0); afr[f][1] = LDA8(a1, f, ck1); }
#pragma unroll
    for (int f = 0; f < 2; ++f) { bfr[f][0] = LDB8(BB1, f, ck0); bfr[f][1] = LDB8(BB1, f, ck1); }
    STG(srcA, kS3, 0, a0);
    SBAR(); LGKM0();
    __builtin_amdgcn_s_setprio(1); MQ(0, 0); __builtin_amdgcn_s_setprio(0);
    SBAR();

    // ph6: quadrant (0,1); stage A(T0+3)h1 -> a0
#pragma unroll
    for (int f = 2; f < 4; ++f) { bfr[f][0] = LDB8(BB1, f, ck0); bfr[f][1] = LDB8(BB1, f, ck1); }
    STG(srcA, kS3, 1, a0);
    SBAR(); LGKM0();
    __builtin_amdgcn_s_setprio(1); MQ(0, 2); __builtin_amdgcn_s_setprio(0);
    SBAR();

    // ph7: quadrant (1,0); stage B(T0+3)h0 -> BB1 (free after ph6)
#pragma unroll
    for (int f = 0; f < 4; ++f) { afr[f][0] = LDA8(a1, f + 4, ck0); afr[f][1] = LDA8(a1, f + 4, ck1); }
    STG(srcB, kS3, 0, BB1);
    SBAR(); LGKM0();
    __builtin_amdgcn_s_setprio(1); MQ(4, 0); __builtin_amdgcn_s_setprio(0);
    SBAR();

    // ph8: quadrant (1,1); stage B(T0+3)h1; vmcnt(8) -> next T0 tile ready
    STG(srcB, kS3, 1, BB1);
    VMCNT(8);
    SBAR();
    __builtin_amdgcn_s_setprio(1); MQ(4, 2); __builtin_amdgcn_s_setprio(0);
    SBAR();

    int tmp = a2; a2 = a1; a1 = a0; a0 = tmp;   // (a0,a1,a2) <- (a2,a0,a1)
  }
  asm volatile("s_waitcnt vmcnt(0)" ::: "memory");  // drain dangling DMA

  // Epilogue: C/D layout col=lane&15, row=(lane>>4)*4+q
  const int orow = (lane >> 4) * 4;
  const long row0 = brow0 + wr * 128;
  const long col0 = bcol0 + wc * 64;
  const long obase = (MODE == 2) ? (long)split * M * N : 0;
#pragma unroll
  for (int fj = 0; fj < 4; ++fj) {
    const long col = col0 + fj * 16 + fr;
    const float bv = (MODE == 2) ? 0.0f : posit_quant_f32(bias[col]);
#pragma unroll
    for (int fi = 0; fi < 8; ++fi) {
#pragma unroll
      for (int q = 0; q < 4; ++q) {
        float v = acc[fi][fj][q];
        if (MODE != 2) {
          v = posit_quant_f32(v + bv);
          if (MODE == 0) v = fmaxf(v, 0.0f);
        }
        const long idx = obase + (row0 + fi * 16 + orow + q) * (long)N + col;
        if (MODE == 0) ((bf16*)out)[idx] = __float2bfloat16(v);
        else           ((float*)out)[idx] = v;
      }
    }
  }
}

// ===========================================================================
// Round-1 128x128 m97-structure kernel (fallback for L2 if ws too small)
// ===========================================================================
#define GBM 128
#define GBN 128
#define GBK 32

__device__ __forceinline__ void gload_lds16(const void* g, void* l) {
  __builtin_amdgcn_global_load_lds((const gu32*)g, (lu32*)l, 16, 0, 0);
}

template <bool RELU, bool OUTBF16>
__global__ __launch_bounds__(256, 2) void gemm_bt_posit(
    const bf16* __restrict__ A, const bf16* __restrict__ B,
    const float* __restrict__ bias, void* __restrict__ out,
    int M, int N, int K) {
  __shared__ __align__(1024) bf16 sA[GBM][GBK];
  __shared__ __align__(1024) bf16 sB[GBN][GBK];

  const int tid = threadIdx.x;
  const int lane = tid & 63;
  const int wave = tid >> 6;
  const int wr = wave >> 1;
  const int wc = wave & 1;
  const long brow0 = (long)blockIdx.y * GBM;
  const long bcol0 = (long)blockIdx.x * GBN;

  const int srow = lane >> 2;
  const int scol = (lane & 3) * 8;
  const int seg0 = wave * 2;

  const bf16* gA0 = A + (brow0 + seg0 * 16 + srow) * (long)K + scol;
  const bf16* gA1 = A + (brow0 + seg0 * 16 + 16 + srow) * (long)K + scol;
  const bf16* gB0 = B + (bcol0 + seg0 * 16 + srow) * (long)K + scol;
  const bf16* gB1 = B + (bcol0 + seg0 * 16 + 16 + srow) * (long)K + scol;
  bf16* lA0 = (bf16*)sA + seg0 * 512;
  bf16* lA1 = lA0 + 512;
  bf16* lB0 = (bf16*)sB + seg0 * 512;
  bf16* lB1 = lB0 + 512;

  f32x4 acc[4][4] = {};
  const int fr = lane & 15;
  const int fk = (lane >> 4) * 8;

  for (int kt = 0; kt < K; kt += GBK) {
    __syncthreads();
    gload_lds16(gA0 + kt, lA0);
    gload_lds16(gA1 + kt, lA1);
    gload_lds16(gB0 + kt, lB0);
    gload_lds16(gB1 + kt, lB1);
    __syncthreads();

    short8 af[4], bfv[4];
#pragma unroll
    for (int i = 0; i < 4; ++i) af[i] = *(const short8*)&sA[wr * 64 + i * 16 + fr][fk];
#pragma unroll
    for (int j = 0; j < 4; ++j) bfv[j] = *(const short8*)&sB[wc * 64 + j * 16 + fr][fk];
#pragma unroll
    for (int i = 0; i < 4; ++i)
#pragma unroll
      for (int j = 0; j < 4; ++j)
        acc[i][j] = __builtin_amdgcn_mfma_f32_16x16x32_bf16(af[i], bfv[j], acc[i][j], 0, 0, 0);
  }

  const int orow = (lane >> 4) * 4;
  const long row0 = brow0 + wr * 64;
  const long col0 = bcol0 + wc * 64;
#pragma unroll
  for (int j = 0; j < 4; ++j) {
    const long col = col0 + j * 16 + fr;
    const float bv = posit_quant_f32(bias[col]);
#pragma unroll
    for (int i = 0; i < 4; ++i) {
#pragma unroll
      for (int q = 0; q < 4; ++q) {
        float v = posit_quant_f32(acc[i][j][q] + bv);
        if (RELU) v = fmaxf(v, 0.0f);
        const long idx = (row0 + i * 16 + orow + q) * (long)N + col;
        if (OUTBF16) ((bf16*)out)[idx] = __float2bfloat16(v);
        else         ((float*)out)[idx] = v;
      }
    }
  }
}

// ---------------------------------------------------------------------------
extern "C" void kernel_launch(void* const* d_in, const int* in_sizes, int n_in,
                              void* d_out, int out_size, void* d_ws, size_t ws_size,
                              hipStream_t stream) {
  const float* x  = (const float*)d_in[0];
  const float* W0 = (const float*)d_in[1];
  const float* b0 = (const float*)d_in[2];
  const float* W1 = (const float*)d_in[3];
  const float* b1 = (const float*)d_in[4];
  const float* W2 = (const float*)d_in[5];
  const float* b2 = (const float*)d_in[6];

  const int M = 4096, D0 = 2048, D1 = 8192, D2 = 8192, DO = 2048;

  char* ws = (char*)d_ws;
  size_t off = 0;
  auto alloc = [&](size_t bytes) {
    char* p = ws + off;
    off += (bytes + 255) & ~(size_t)255;
    return p;
  };
  bf16* xq  = (bf16*)alloc((size_t)M * D0 * 2);
  bf16* W0q = (bf16*)alloc((size_t)D1 * D0 * 2);
  bf16* W1q = (bf16*)alloc((size_t)D2 * D1 * 2);
  bf16* W2q = (bf16*)alloc((size_t)DO * D2 * 2);
  bf16* h0  = (bf16*)alloc((size_t)M * D1 * 2);
  bf16* h1  = (bf16*)alloc((size_t)M * D2 * 2);
  float* part = (float*)alloc((size_t)2 * M * DO * 4);   // split-K partials
  const bool splitk = (off <= ws_size);
  (void)in_sizes; (void)n_in; (void)out_size;

  auto quant = [&](const float* in, bf16* outp, long n) {
    long n4 = n / 4;
    long want = (n4 + 255) / 256;
    int blocks = (int)(want < 2048 ? want : 2048);
    kquant_bf16<<<blocks, 256, 0, stream>>>(in, outp, n4);
  };
  quant(x,  xq,  (long)M * D0);
  quant(W0, W0q, (long)D1 * D0);
  quant(W1, W1q, (long)D2 * D1);
  quant(W2, W2q, (long)DO * D2);

  // L0: h0 = relu(pq(xq @ W0q^T + pq(b0)))   M=4096 N=8192 K=2048
  {
    int nbt = (D1 / 256) * (M / 256), nwg = nbt;
    gemm256_posit<0><<<dim3(nwg), dim3(512), 0, stream>>>(
        xq, W0q, b0, h0, M, D1, D0, D0, nbt, nwg / 8);
  }
  // L1: h1 = relu(pq(h0 @ W1q^T + pq(b1)))   M=4096 N=8192 K=8192
  {
    int nbt = (D2 / 256) * (M / 256), nwg = nbt;
    gemm256_posit<0><<<dim3(nwg), dim3(512), 0, stream>>>(
        h0, W1q, b1, h1, M, D2, D1, D1, nbt, nwg / 8);
  }
  // L2: out = pq(h1 @ W2q^T + pq(b2))  f32   M=4096 N=2048 K=8192
  if (splitk) {
    int nbt = (DO / 256) * (M / 256);      // 128 tiles per split
    int nwg = nbt * 2;                     // 256 blocks, full occupancy
    gemm256_posit<2><<<dim3(nwg), dim3(512), 0, stream>>>(
        h1, W2q, nullptr, part, M, DO, D2, D2 / 2, nbt, nwg / 8);
    long n4 = (long)M * DO / 4;
    kcombine<<<2048, 256, 0, stream>>>(part, b2, (float*)d_out, n4,
                                       (long)M * DO, DO / 4 - 1);
  } else {
    gemm_bt_posit<false, false><<<dim3(DO / GBN, M / GBM), dim3(256), 0, stream>>>(
        h1, W2q, b2, (float*)d_out, M, DO, D2);
  }
}